// Round 18
// baseline (144.072 us; speedup 1.0000x reference)
//
#include <hip/hip_runtime.h>
#include <hip/hip_bf16.h>
#include <math.h>

#define LEN_IN   16660
#define D_MODEL  256
#define N_HEADS  8

typedef __attribute__((ext_vector_type(8))) short short8v;
typedef __attribute__((ext_vector_type(4))) float f32x4;
typedef _Float16 f16x2 __attribute__((ext_vector_type(2)));
typedef _Float16 f16x8 __attribute__((ext_vector_type(8)));

__device__ __forceinline__ unsigned short f2h(float f) {
  union { unsigned short u; _Float16 h; } c;
  c.h = (_Float16)f;
  return c.u;
}
__device__ __forceinline__ float h2f(unsigned short u) {
  union { unsigned short u; _Float16 h; } c;
  c.u = u;
  return (float)c.h;
}
__device__ __forceinline__ f16x2 u2h(unsigned u) {
  union { unsigned u; f16x2 h; } c;
  c.u = u;
  return c.h;
}

// ---------------------------------------------------------------------------
// Mega-prep (R16-proven): cvt inp f32->f16 (blocks 0..2047); weight transpose
// (2048..2127, Woff slot skipped); bqo (2128); Wqo GEMM (2129..2144).
// ---------------------------------------------------------------------------
__global__ __launch_bounds__(256) void mega_prep(
    const float* __restrict__ inp,
    const float* __restrict__ Wq, const float* __restrict__ Wk,
    const float* __restrict__ Wv, const float* __restrict__ Woff,
    const float* __restrict__ Wo,
    const float* __restrict__ bq, const float* __restrict__ boff,
    unsigned short* __restrict__ in16,
    unsigned short* __restrict__ Btq, unsigned short* __restrict__ Btk,
    unsigned short* __restrict__ Btv, unsigned short* __restrict__ Bto,
    unsigned short* __restrict__ Btqo, float* __restrict__ bqo) {
  int b = blockIdx.x;
  int tid = threadIdx.x;

  if (b < 2048) {  // ---- cvt16 (inp only) ----
    const int nq = (LEN_IN * D_MODEL) / 4;
    int i = b * 256 + tid;
    const int stride = 2048 * 256;
    for (int qd = i; qd < nq; qd += stride) {
      float4 vb = ((const float4*)inp)[qd];
      ushort4 hb = {f2h(vb.x), f2h(vb.y), f2h(vb.z), f2h(vb.w)};
      ((ushort4*)in16)[qd] = hb;
    }
    return;
  }

  if (b < 2128) {  // ---- weight transpose ----
    __shared__ float tile[64][65];
    int bb = b - 2048;
    int mat = bb >> 4, t = bb & 15;
    int ti = t >> 2, tj = t & 3;
    if (mat == 3) return;  // Btoff not needed (wqo transposes Woff itself)
    const float* W = (mat == 0) ? Wq : (mat == 1) ? Wk : (mat == 2) ? Wv : Wo;
    unsigned short* Bt = (mat == 0) ? Btq : (mat == 1) ? Btk : (mat == 2) ? Btv : Bto;
    #pragma unroll
    for (int i = 0; i < 16; i++) {
      int idx = tid + i * 256;
      int kr = idx >> 6, nc = idx & 63;
      tile[kr][nc] = W[(size_t)(ti * 64 + kr) * 256 + tj * 64 + nc];
    }
    __syncthreads();
    #pragma unroll
    for (int i = 0; i < 16; i++) {
      int idx = tid + i * 256;
      int nr = idx >> 6, kc = idx & 63;
      Bt[(size_t)(tj * 64 + nr) * 256 + ti * 64 + kc] = f2h(tile[kc][nr]);
    }
    return;
  }

  if (b == 2128) {  // ---- bqo ----
    float s = boff[tid];
    for (int i = 0; i < 256; i++) s += bq[i] * Woff[(size_t)i * 256 + tid];
    bqo[tid] = s;
    return;
  }

  // ---- wqo: 16 blocks, 64x64 tiles of Wqo = Wq @ Woff ----
  {
    const int P = 40;
    __shared__ short As[64 * P], Bs[64 * P];
    int t = b - 2129;
    int m0 = (t >> 2) * 64, n0 = (t & 3) * 64;
    int w = tid >> 6, l = tid & 63;
    int r = l & 15, g = l >> 4;
    int mi = (w >> 1) * 32, ni = (w & 1) * 32;
    int sm = tid >> 2, sp = tid & 3;
    int kr = tid >> 3, nc = (tid & 7) * 8;

    f32x4 acc[2][2];
    #pragma unroll
    for (int a = 0; a < 2; a++)
      #pragma unroll
      for (int c = 0; c < 2; c++) acc[a][c] = (f32x4){0.f, 0.f, 0.f, 0.f};

    for (int k0 = 0; k0 < 256; k0 += 32) {
      const float* src = Wq + (size_t)(m0 + sm) * 256 + k0 + sp * 8;
      float4 u0 = *(const float4*)src;
      float4 u1 = *(const float4*)(src + 4);
      f16x8 hv = {(_Float16)u0.x, (_Float16)u0.y, (_Float16)u0.z, (_Float16)u0.w,
                  (_Float16)u1.x, (_Float16)u1.y, (_Float16)u1.z, (_Float16)u1.w};
      *(f16x8*)&As[sm * P + sp * 8] = hv;
      const float* wsrc = Woff + (size_t)(k0 + kr) * 256 + n0 + nc;
      float4 w0 = *(const float4*)wsrc;
      float4 w1 = *(const float4*)(wsrc + 4);
      Bs[(nc + 0) * P + kr] = (short)f2h(w0.x);
      Bs[(nc + 1) * P + kr] = (short)f2h(w0.y);
      Bs[(nc + 2) * P + kr] = (short)f2h(w0.z);
      Bs[(nc + 3) * P + kr] = (short)f2h(w0.w);
      Bs[(nc + 4) * P + kr] = (short)f2h(w1.x);
      Bs[(nc + 5) * P + kr] = (short)f2h(w1.y);
      Bs[(nc + 6) * P + kr] = (short)f2h(w1.z);
      Bs[(nc + 7) * P + kr] = (short)f2h(w1.w);
      __syncthreads();
      f16x8 af[2], bf[2];
      #pragma unroll
      for (int a = 0; a < 2; a++)
        af[a] = *(f16x8*)&As[(mi + a * 16 + r) * P + g * 8];
      #pragma unroll
      for (int c = 0; c < 2; c++)
        bf[c] = *(f16x8*)&Bs[(ni + c * 16 + r) * P + g * 8];
      #pragma unroll
      for (int a = 0; a < 2; a++)
        #pragma unroll
        for (int c = 0; c < 2; c++)
          acc[a][c] = __builtin_amdgcn_mfma_f32_16x16x32_f16(af[a], bf[c], acc[a][c], 0, 0, 0);
      __syncthreads();
    }
    #pragma unroll
    for (int a = 0; a < 2; a++)
      #pragma unroll
      for (int c = 0; c < 2; c++) {
        int col = n0 + ni + c * 16 + r;
        #pragma unroll
        for (int i = 0; i < 4; i++) {
          int row = m0 + mi + a * 16 + g * 4 + i;
          Btqo[(size_t)col * 256 + row] = f2h(acc[a][c][i]);  // transposed
        }
      }
  }
}

// ---------------------------------------------------------------------------
// Fused projections (R16-proven), dual-B z-slices, 128x64 tile, BK=64:
// z=0: A=query (f32, cvt in staging), B={Btq,Btqo} -> qp(f16), offs(f16)
// z=1: A=in16 (f16),                 B={Btk,Btv}  -> head-major packed kv
// ---------------------------------------------------------------------------
__global__ __launch_bounds__(256) void gemm_qkv(
    const float* __restrict__ queryF, const unsigned short* __restrict__ in16,
    const unsigned short* __restrict__ Btq,
    const unsigned short* __restrict__ Btk,
    const unsigned short* __restrict__ Btv,
    const unsigned short* __restrict__ Btqo,
    const float* __restrict__ bq, const float* __restrict__ bk,
    const float* __restrict__ bv, const float* __restrict__ bqo,
    unsigned short* __restrict__ qp_out, unsigned* __restrict__ kv_out,
    unsigned short* __restrict__ offs_out, int M) {
  const int P = 72;
  __shared__ short As[128 * P], B1[64 * P], B2[64 * P];
  int z = blockIdx.z;
  const unsigned short* Bt1 = (z == 0) ? Btq : Btk;
  const unsigned short* Bt2 = (z == 0) ? Btqo : Btv;
  int tid = threadIdx.x;
  int m0 = blockIdx.x * 128, n0 = blockIdx.y * 64;
  int w = tid >> 6, l = tid & 63;
  int r = l & 15, g = l >> 4;
  int mi = (w >> 1) * 64, ni = (w & 1) * 32;
  int arow = tid >> 1, ach = (tid & 1) * 32;
  int brow = tid >> 2, bch = (tid & 3) * 16;

  f32x4 acc1[4][2], acc2[4][2];
  #pragma unroll
  for (int a = 0; a < 4; a++)
    #pragma unroll
    for (int b = 0; b < 2; b++) {
      acc1[a][b] = (f32x4){0.f, 0.f, 0.f, 0.f};
      acc2[a][b] = (f32x4){0.f, 0.f, 0.f, 0.f};
    }

  for (int k0 = 0; k0 < 256; k0 += 64) {
    int gm = m0 + arow;
    if (z == 0) {
      #pragma unroll
      for (int t = 0; t < 4; t++) {
        f16x8 hv = {0, 0, 0, 0, 0, 0, 0, 0};
        if (gm < M) {
          const float* src = queryF + (size_t)gm * 256 + k0 + ach + t * 8;
          float4 u0 = *(const float4*)src;
          float4 u1 = *(const float4*)(src + 4);
          hv = (f16x8){(_Float16)u0.x, (_Float16)u0.y, (_Float16)u0.z, (_Float16)u0.w,
                       (_Float16)u1.x, (_Float16)u1.y, (_Float16)u1.z, (_Float16)u1.w};
        }
        *(f16x8*)&As[arow * P + ach + t * 8] = hv;
      }
    } else {
      short8v a0 = {0,0,0,0,0,0,0,0}, a1 = a0, a2 = a0, a3 = a0;
      if (gm < M) {
        const unsigned short* src = in16 + (size_t)gm * 256 + k0 + ach;
        a0 = *(const short8v*)src;
        a1 = *(const short8v*)(src + 8);
        a2 = *(const short8v*)(src + 16);
        a3 = *(const short8v*)(src + 24);
      }
      *(short8v*)&As[arow * P + ach] = a0;
      *(short8v*)&As[arow * P + ach + 8] = a1;
      *(short8v*)&As[arow * P + ach + 16] = a2;
      *(short8v*)&As[arow * P + ach + 24] = a3;
    }
    {
      const unsigned short* bsrc = Bt1 + (size_t)(n0 + brow) * 256 + k0 + bch;
      *(short8v*)&B1[brow * P + bch] = *(const short8v*)bsrc;
      *(short8v*)&B1[brow * P + bch + 8] = *(const short8v*)(bsrc + 8);
      const unsigned short* bsrc2 = Bt2 + (size_t)(n0 + brow) * 256 + k0 + bch;
      *(short8v*)&B2[brow * P + bch] = *(const short8v*)bsrc2;
      *(short8v*)&B2[brow * P + bch + 8] = *(const short8v*)(bsrc2 + 8);
    }
    __syncthreads();

    f16x8 af[4][2], b1f[2][2], b2f[2][2];
    #pragma unroll
    for (int a = 0; a < 4; a++)
      #pragma unroll
      for (int ks = 0; ks < 2; ks++)
        af[a][ks] = *(f16x8*)&As[(mi + a * 16 + r) * P + ks * 32 + g * 8];
    #pragma unroll
    for (int b = 0; b < 2; b++)
      #pragma unroll
      for (int ks = 0; ks < 2; ks++) {
        b1f[b][ks] = *(f16x8*)&B1[(ni + b * 16 + r) * P + ks * 32 + g * 8];
        b2f[b][ks] = *(f16x8*)&B2[(ni + b * 16 + r) * P + ks * 32 + g * 8];
      }
    #pragma unroll
    for (int a = 0; a < 4; a++)
      #pragma unroll
      for (int b = 0; b < 2; b++)
        #pragma unroll
        for (int ks = 0; ks < 2; ks++) {
          acc1[a][b] = __builtin_amdgcn_mfma_f32_16x16x32_f16(af[a][ks], b1f[b][ks], acc1[a][b], 0, 0, 0);
          acc2[a][b] = __builtin_amdgcn_mfma_f32_16x16x32_f16(af[a][ks], b2f[b][ks], acc2[a][b], 0, 0, 0);
        }
    __syncthreads();
  }

  #pragma unroll
  for (int a = 0; a < 4; a++)
    #pragma unroll
    for (int b = 0; b < 2; b++) {
      int col = n0 + ni + b * 16 + r;
      if (z == 0) {
        float bc1 = bq[col], bc2 = bqo[col];
        #pragma unroll
        for (int i = 0; i < 4; i++) {
          int row = m0 + mi + a * 16 + g * 4 + i;
          if (row < M) {
            qp_out[(size_t)row * 256 + col] = f2h(acc1[a][b][i] + bc1);
            offs_out[(size_t)row * 256 + col] = f2h(acc2[a][b][i] + bc2);
          }
        }
      } else {
        float bkc = bk[col], bvc = bv[col];
        int hh = col >> 5, cc = col & 31;
        #pragma unroll
        for (int i = 0; i < 4; i++) {
          int row = m0 + mi + a * 16 + g * 4 + i;
          if (row < M) {
            unsigned kh = f2h(acc1[a][b][i] + bkc);
            unsigned vh = f2h(acc2[a][b][i] + bvc);
            kv_out[((size_t)hh * LEN_IN + row) * 32 + cc] = kh | (vh << 16);
          }
        }
      }
    }
}

// ---------------------------------------------------------------------------
// Output projection (R16-proven): A f16 (attn), f32 out, 128x64 tile BK=64.
// ---------------------------------------------------------------------------
__global__ __launch_bounds__(256) void gemm_out(
    const unsigned short* __restrict__ A,
    const unsigned short* __restrict__ Bt,
    const float* __restrict__ bias, float* __restrict__ C, int M) {
  const int P = 72;
  __shared__ short As[128 * P], Bs[64 * P];
  int tid = threadIdx.x;
  int m0 = blockIdx.x * 128, n0 = blockIdx.y * 64;
  int w = tid >> 6, l = tid & 63;
  int r = l & 15, g = l >> 4;
  int mi = (w >> 1) * 64, ni = (w & 1) * 32;
  int arow = tid >> 1, ach = (tid & 1) * 32;
  int brow = tid >> 2, bch = (tid & 3) * 16;

  f32x4 acc[4][2];
  #pragma unroll
  for (int a = 0; a < 4; a++)
    #pragma unroll
    for (int b = 0; b < 2; b++) acc[a][b] = (f32x4){0.f, 0.f, 0.f, 0.f};

  for (int k0 = 0; k0 < 256; k0 += 64) {
    int gm = m0 + arow;
    short8v a0 = {0,0,0,0,0,0,0,0}, a1 = a0, a2 = a0, a3 = a0;
    if (gm < M) {
      const unsigned short* src = A + (size_t)gm * 256 + k0 + ach;
      a0 = *(const short8v*)src;
      a1 = *(const short8v*)(src + 8);
      a2 = *(const short8v*)(src + 16);
      a3 = *(const short8v*)(src + 24);
    }
    *(short8v*)&As[arow * P + ach] = a0;
    *(short8v*)&As[arow * P + ach + 8] = a1;
    *(short8v*)&As[arow * P + ach + 16] = a2;
    *(short8v*)&As[arow * P + ach + 24] = a3;
    const unsigned short* bsrc = Bt + (size_t)(n0 + brow) * 256 + k0 + bch;
    *(short8v*)&Bs[brow * P + bch] = *(const short8v*)bsrc;
    *(short8v*)&Bs[brow * P + bch + 8] = *(const short8v*)(bsrc + 8);
    __syncthreads();

    f16x8 af[4][2], bf[2][2];
    #pragma unroll
    for (int a = 0; a < 4; a++)
      #pragma unroll
      for (int ks = 0; ks < 2; ks++)
        af[a][ks] = *(f16x8*)&As[(mi + a * 16 + r) * P + ks * 32 + g * 8];
    #pragma unroll
    for (int b = 0; b < 2; b++)
      #pragma unroll
      for (int ks = 0; ks < 2; ks++)
        bf[b][ks] = *(f16x8*)&Bs[(ni + b * 16 + r) * P + ks * 32 + g * 8];
    #pragma unroll
    for (int a = 0; a < 4; a++)
      #pragma unroll
      for (int b = 0; b < 2; b++)
        #pragma unroll
        for (int ks = 0; ks < 2; ks++)
          acc[a][b] = __builtin_amdgcn_mfma_f32_16x16x32_f16(af[a][ks], bf[b][ks], acc[a][b], 0, 0, 0);
    __syncthreads();
  }
  #pragma unroll
  for (int a = 0; a < 4; a++)
    #pragma unroll
    for (int b = 0; b < 2; b++) {
      int col = n0 + ni + b * 16 + r;
      float bc = bias[col];
      #pragma unroll
      for (int i = 0; i < 4; i++) {
        int row = m0 + mi + a * 16 + g * 4 + i;
        if (row < M) C[(size_t)row * 256 + col] = acc[a][b][i] + bc;
      }
    }
}

// ---------------------------------------------------------------------------
// Sampling + attention v10: TWO (q,h) per wave with PACKED interleaved kv
// (de-confounded retry of R10 — split planes were the real FETCH problem).
// lane = qin(lane>>5) x pt((lane&31)>>1) x chunk((lane&1)*16 channels).
// Per-wave fixed overhead (setup/softmax/output) amortized over 2 queries.
// ---------------------------------------------------------------------------
__global__ __launch_bounds__(256) void sample_attn(
    const unsigned short* __restrict__ qp,    // f16 (LEN,256)
    const unsigned short* __restrict__ offs,  // f16 (LEN,256)
    const float* __restrict__ rp,             // f32 (LEN,8)
    const unsigned* __restrict__ kv,          // packed f16 {k|v<<16}, [h][pix][32]
    unsigned short* __restrict__ attn_out) {  // f16 (LEN,256)
  __shared__ float vbuf[4][2][16][36];

  int tid = threadIdx.x;
  int wslot = tid >> 6;
  int lane = tid & 63;
  int qin = lane >> 5;
  int l5 = lane & 31;
  int pt = l5 >> 1;          // point 0..15
  int c16 = (l5 & 1) * 16;   // channel chunk base (16 channels per lane)
  int wid = blockIdx.x * 8 + wslot * 2 + qin;
  int q = wid >> 3;
  int h = wid & 7;

  int l = pt >> 2;
  int W = 112 >> l;
  int start = (int)((50176u - (50176u >> (2 * l))) / 3u);  // 0,12544,15680,16464

  f16x2 offp = u2h(*(const unsigned*)(offs + (size_t)q * 256 + h * 32 + pt * 2));
  float2 rpp = *(const float2*)(rp + (size_t)q * 8 + l * 2);

  float x = rpp.x * (float)W + (float)offp[0] - 0.5f;
  float y = rpp.y * (float)W + (float)offp[1] - 0.5f;
  float x0f = floorf(x), y0f = floorf(y);
  float lx = x - x0f, ly = y - y0f;
  int x0 = (int)x0f, y0 = (int)y0f;
  float wx0 = 1.f - lx, wy0 = 1.f - ly;

  int Wm1 = W - 1;
  int x0c = min(max(x0, 0), Wm1), x1c = min(max(x0 + 1, 0), Wm1);
  int y0c = min(max(y0, 0), Wm1), y1c = min(max(y0 + 1, 0), Wm1);
  bool x0v = (unsigned)x0 < (unsigned)W, x1v = (unsigned)(x0 + 1) < (unsigned)W;
  bool y0v = (unsigned)y0 < (unsigned)W, y1v = (unsigned)(y0 + 1) < (unsigned)W;
  float w00 = (x0v && y0v) ? wy0 * wx0 : 0.f;
  float w01 = (x1v && y0v) ? wy0 * lx : 0.f;
  float w10 = (x0v && y1v) ? ly * wx0 : 0.f;
  float w11 = (x1v && y1v) ? ly * lx : 0.f;

  const unsigned* kvh = kv + (size_t)h * LEN_IN * 32 + c16;
  const unsigned* row0 = kvh + (size_t)(start + y0c * W) * 32;
  const unsigned* row1 = kvh + (size_t)(start + y1c * W) * 32;
  const unsigned* taddr[4] = {row0 + (size_t)x0c * 32, row0 + (size_t)x1c * 32,
                              row1 + (size_t)x0c * 32, row1 + (size_t)x1c * 32};
  float twgt[4] = {w00, w01, w10, w11};

  f16x2 acc[16];
  #pragma unroll
  for (int j = 0; j < 16; j++) acc[j] = (f16x2){(_Float16)0.f, (_Float16)0.f};

  #pragma unroll
  for (int tap = 0; tap < 4; tap++) {
    uint4 u0 = *(const uint4*)taddr[tap];
    uint4 u1 = *(const uint4*)(taddr[tap] + 4);
    uint4 u2 = *(const uint4*)(taddr[tap] + 8);
    uint4 u3 = *(const uint4*)(taddr[tap] + 12);
    _Float16 wh = (_Float16)twgt[tap];
    f16x2 w2 = {wh, wh};
    acc[0]  += w2 * u2h(u0.x);  acc[1]  += w2 * u2h(u0.y);
    acc[2]  += w2 * u2h(u0.z);  acc[3]  += w2 * u2h(u0.w);
    acc[4]  += w2 * u2h(u1.x);  acc[5]  += w2 * u2h(u1.y);
    acc[6]  += w2 * u2h(u1.z);  acc[7]  += w2 * u2h(u1.w);
    acc[8]  += w2 * u2h(u2.x);  acc[9]  += w2 * u2h(u2.y);
    acc[10] += w2 * u2h(u2.z);  acc[11] += w2 * u2h(u2.w);
    acc[12] += w2 * u2h(u3.x);  acc[13] += w2 * u2h(u3.y);
    acc[14] += w2 * u2h(u3.z);  acc[15] += w2 * u2h(u3.w);
  }

  // q . k over this lane's 16 channels via fdot2 (k = low halves)
  const uint4* qsrc = (const uint4*)(qp + (size_t)q * 256 + h * 32 + c16);
  uint4 qa = qsrc[0], qb = qsrc[1];
  float dot = 0.f;
  f16x2 kp;
  kp[0] = acc[0][0];  kp[1] = acc[1][0];
  dot = __builtin_amdgcn_fdot2(u2h(qa.x), kp, dot, false);
  kp[0] = acc[2][0];  kp[1] = acc[3][0];
  dot = __builtin_amdgcn_fdot2(u2h(qa.y), kp, dot, false);
  kp[0] = acc[4][0];  kp[1] = acc[5][0];
  dot = __builtin_amdgcn_fdot2(u2h(qa.z), kp, dot, false);
  kp[0] = acc[6][0];  kp[1] = acc[7][0];
  dot = __builtin_amdgcn_fdot2(u2h(qa.w), kp, dot, false);
  kp[0] = acc[8][0];  kp[1] = acc[9][0];
  dot = __builtin_amdgcn_fdot2(u2h(qb.x), kp, dot, false);
  kp[0] = acc[10][0]; kp[1] = acc[11][0];
  dot = __builtin_amdgcn_fdot2(u2h(qb.y), kp, dot, false);
  kp[0] = acc[12][0]; kp[1] = acc[13][0];
  dot = __builtin_amdgcn_fdot2(u2h(qb.z), kp, dot, false);
  kp[0] = acc[14][0]; kp[1] = acc[15][0];
  dot = __builtin_amdgcn_fdot2(u2h(qb.w), kp, dot, false);
  dot += __shfl_xor(dot, 1, 64);   // merge the 2 chunk lanes

  // register softmax across 16 point-lane-pairs (strides 2..16 keep qin half)
  float e = __expf(dot * 0.17677669529663687f);
  float s = e;
  s += __shfl_xor(s, 2, 64);
  s += __shfl_xor(s, 4, 64);
  s += __shfl_xor(s, 8, 64);
  s += __shfl_xor(s, 16, 64);
  float wsc = e / s;

  // softmax-scaled v (high halves) to LDS: 16 floats per lane
  float4 o0 = {wsc * (float)acc[0][1],  wsc * (float)acc[1][1],
               wsc * (float)acc[2][1],  wsc * (float)acc[3][1]};
  float4 o1 = {wsc * (float)acc[4][1],  wsc * (float)acc[5][1],
               wsc * (float)acc[6][1],  wsc * (float)acc[7][1]};
  float4 o2 = {wsc * (float)acc[8][1],  wsc * (float)acc[9][1],
               wsc * (float)acc[10][1], wsc * (float)acc[11][1]};
  float4 o3 = {wsc * (float)acc[12][1], wsc * (float)acc[13][1],
               wsc * (float)acc[14][1], wsc * (float)acc[15][1]};
  float* vdst = &vbuf[wslot][qin][pt][c16];
  *(float4*)(vdst + 0) = o0;
  *(float4*)(vdst + 4) = o1;
  *(float4*)(vdst + 8) = o2;
  *(float4*)(vdst + 12) = o3;
  __syncthreads();

  // output: lane = (query qo, channel c); 16 LDS reads
  int qo = lane >> 5;
  int c = lane & 31;
  float o = 0.f;
  #pragma unroll
  for (int p = 0; p < 16; p++) o += vbuf[wslot][qo][p][c];
  int wid2 = blockIdx.x * 8 + wslot * 2 + qo;
  attn_out[(size_t)(wid2 >> 3) * 256 + (wid2 & 7) * 32 + c] = f2h(o);
}

extern "C" void kernel_launch(void* const* d_in, const int* in_sizes, int n_in,
                              void* d_out, int out_size, void* d_ws, size_t ws_size,
                              hipStream_t stream) {
  const float* query = (const float*)d_in[0];
  const float* rp    = (const float*)d_in[1];
  const float* inp   = (const float*)d_in[2];
  const float* W_q   = (const float*)d_in[5];
  const float* b_q   = (const float*)d_in[6];
  const float* W_k   = (const float*)d_in[7];
  const float* b_k   = (const float*)d_in[8];
  const float* W_v   = (const float*)d_in[9];
  const float* b_v   = (const float*)d_in[10];
  const float* W_o   = (const float*)d_in[11];
  const float* b_o   = (const float*)d_in[12];
  const float* W_off = (const float*)d_in[13];
  const float* b_off = (const float*)d_in[14];
  float* out = (float*)d_out;

  const size_t nelem = (size_t)LEN_IN * D_MODEL;  // 4,264,960
  unsigned short* in16  = (unsigned short*)d_ws;
  unsigned short* qp    = in16 + nelem;
  unsigned short* offsb = qp + nelem;
  unsigned short* attn  = offsb + nelem;
  unsigned* kvp = (unsigned*)(attn + nelem);
  unsigned short* Btq   = (unsigned short*)(kvp + nelem);
  unsigned short* Btk   = Btq + 256 * 256;
  unsigned short* Btv   = Btk + 256 * 256;
  unsigned short* Bto   = Btv + 256 * 256;
  unsigned short* Btqo  = Bto + 256 * 256;
  float* bqo = (float*)(Btqo + 256 * 256);

  dim3 blk(256);
  dim3 ggrid((LEN_IN + 127) / 128, D_MODEL / 64);      // (131, 4)
  dim3 ggrid2((LEN_IN + 127) / 128, D_MODEL / 64, 2);  // {q+off, kv}

  mega_prep<<<2145, blk, 0, stream>>>(inp, W_q, W_k, W_v, W_off, W_o,
                                      b_q, b_off, in16,
                                      Btq, Btk, Btv, Bto, Btqo, bqo);

  gemm_qkv<<<ggrid2, blk, 0, stream>>>(query, in16, Btq, Btk, Btv, Btqo,
                                       b_q, b_k, b_v, bqo,
                                       qp, kvp, offsb, LEN_IN);

  sample_attn<<<LEN_IN, blk, 0, stream>>>(qp, offsb, rp, kvp, attn);

  gemm_out<<<ggrid, blk, 0, stream>>>(attn, Bto, b_o, out, LEN_IN);
}

// Round 19
// 115.971 us; speedup vs baseline: 1.2423x; 1.2423x over previous
//
#include <hip/hip_runtime.h>
#include <hip/hip_bf16.h>
#include <math.h>

#define LEN_IN   16660
#define D_MODEL  256
#define N_HEADS  8

typedef __attribute__((ext_vector_type(8))) short short8v;
typedef __attribute__((ext_vector_type(4))) float f32x4;
typedef _Float16 f16x2 __attribute__((ext_vector_type(2)));
typedef _Float16 f16x8 __attribute__((ext_vector_type(8)));

__device__ __forceinline__ unsigned short f2h(float f) {
  union { unsigned short u; _Float16 h; } c;
  c.h = (_Float16)f;
  return c.u;
}
__device__ __forceinline__ float h2f(unsigned short u) {
  union { unsigned short u; _Float16 h; } c;
  c.u = u;
  return (float)c.h;
}
__device__ __forceinline__ f16x2 u2h(unsigned u) {
  union { unsigned u; f16x2 h; } c;
  c.u = u;
  return c.h;
}

// ---------------------------------------------------------------------------
// Mega-prep: cvt inp f32->f16 (blocks 0..2047); weight transpose (2048..2127,
// Woff slot skipped); bqo (2128); Wqo GEMM (2129..2144).
// ---------------------------------------------------------------------------
__global__ __launch_bounds__(256) void mega_prep(
    const float* __restrict__ inp,
    const float* __restrict__ Wq, const float* __restrict__ Wk,
    const float* __restrict__ Wv, const float* __restrict__ Woff,
    const float* __restrict__ Wo,
    const float* __restrict__ bq, const float* __restrict__ boff,
    unsigned short* __restrict__ in16,
    unsigned short* __restrict__ Btq, unsigned short* __restrict__ Btk,
    unsigned short* __restrict__ Btv, unsigned short* __restrict__ Bto,
    unsigned short* __restrict__ Btqo, float* __restrict__ bqo) {
  int b = blockIdx.x;
  int tid = threadIdx.x;

  if (b < 2048) {  // ---- cvt16 (inp only) ----
    const int nq = (LEN_IN * D_MODEL) / 4;
    int i = b * 256 + tid;
    const int stride = 2048 * 256;
    for (int qd = i; qd < nq; qd += stride) {
      float4 vb = ((const float4*)inp)[qd];
      ushort4 hb = {f2h(vb.x), f2h(vb.y), f2h(vb.z), f2h(vb.w)};
      ((ushort4*)in16)[qd] = hb;
    }
    return;
  }

  if (b < 2128) {  // ---- weight transpose ----
    __shared__ float tile[64][65];
    int bb = b - 2048;
    int mat = bb >> 4, t = bb & 15;
    int ti = t >> 2, tj = t & 3;
    if (mat == 3) return;  // Btoff not needed (wqo transposes Woff itself)
    const float* W = (mat == 0) ? Wq : (mat == 1) ? Wk : (mat == 2) ? Wv : Wo;
    unsigned short* Bt = (mat == 0) ? Btq : (mat == 1) ? Btk : (mat == 2) ? Btv : Bto;
    #pragma unroll
    for (int i = 0; i < 16; i++) {
      int idx = tid + i * 256;
      int kr = idx >> 6, nc = idx & 63;
      tile[kr][nc] = W[(size_t)(ti * 64 + kr) * 256 + tj * 64 + nc];
    }
    __syncthreads();
    #pragma unroll
    for (int i = 0; i < 16; i++) {
      int idx = tid + i * 256;
      int nr = idx >> 6, kc = idx & 63;
      Bt[(size_t)(tj * 64 + nr) * 256 + ti * 64 + kc] = f2h(tile[kc][nr]);
    }
    return;
  }

  if (b == 2128) {  // ---- bqo ----
    float s = boff[tid];
    for (int i = 0; i < 256; i++) s += bq[i] * Woff[(size_t)i * 256 + tid];
    bqo[tid] = s;
    return;
  }

  // ---- wqo: 16 blocks, 64x64 tiles of Wqo = Wq @ Woff ----
  {
    const int P = 40;
    __shared__ short As[64 * P], Bs[64 * P];
    int t = b - 2129;
    int m0 = (t >> 2) * 64, n0 = (t & 3) * 64;
    int w = tid >> 6, l = tid & 63;
    int r = l & 15, g = l >> 4;
    int mi = (w >> 1) * 32, ni = (w & 1) * 32;
    int sm = tid >> 2, sp = tid & 3;
    int kr = tid >> 3, nc = (tid & 7) * 8;

    f32x4 acc[2][2];
    #pragma unroll
    for (int a = 0; a < 2; a++)
      #pragma unroll
      for (int c = 0; c < 2; c++) acc[a][c] = (f32x4){0.f, 0.f, 0.f, 0.f};

    for (int k0 = 0; k0 < 256; k0 += 32) {
      const float* src = Wq + (size_t)(m0 + sm) * 256 + k0 + sp * 8;
      float4 u0 = *(const float4*)src;
      float4 u1 = *(const float4*)(src + 4);
      f16x8 hv = {(_Float16)u0.x, (_Float16)u0.y, (_Float16)u0.z, (_Float16)u0.w,
                  (_Float16)u1.x, (_Float16)u1.y, (_Float16)u1.z, (_Float16)u1.w};
      *(f16x8*)&As[sm * P + sp * 8] = hv;
      const float* wsrc = Woff + (size_t)(k0 + kr) * 256 + n0 + nc;
      float4 w0 = *(const float4*)wsrc;
      float4 w1 = *(const float4*)(wsrc + 4);
      Bs[(nc + 0) * P + kr] = (short)f2h(w0.x);
      Bs[(nc + 1) * P + kr] = (short)f2h(w0.y);
      Bs[(nc + 2) * P + kr] = (short)f2h(w0.z);
      Bs[(nc + 3) * P + kr] = (short)f2h(w0.w);
      Bs[(nc + 4) * P + kr] = (short)f2h(w1.x);
      Bs[(nc + 5) * P + kr] = (short)f2h(w1.y);
      Bs[(nc + 6) * P + kr] = (short)f2h(w1.z);
      Bs[(nc + 7) * P + kr] = (short)f2h(w1.w);
      __syncthreads();
      f16x8 af[2], bf[2];
      #pragma unroll
      for (int a = 0; a < 2; a++)
        af[a] = *(f16x8*)&As[(mi + a * 16 + r) * P + g * 8];
      #pragma unroll
      for (int c = 0; c < 2; c++)
        bf[c] = *(f16x8*)&Bs[(ni + c * 16 + r) * P + g * 8];
      #pragma unroll
      for (int a = 0; a < 2; a++)
        #pragma unroll
        for (int c = 0; c < 2; c++)
          acc[a][c] = __builtin_amdgcn_mfma_f32_16x16x32_f16(af[a], bf[c], acc[a][c], 0, 0, 0);
      __syncthreads();
    }
    #pragma unroll
    for (int a = 0; a < 2; a++)
      #pragma unroll
      for (int c = 0; c < 2; c++) {
        int col = n0 + ni + c * 16 + r;
        #pragma unroll
        for (int i = 0; i < 4; i++) {
          int row = m0 + mi + a * 16 + g * 4 + i;
          Btqo[(size_t)col * 256 + row] = f2h(acc[a][c][i]);  // transposed
        }
      }
  }
}

// ---------------------------------------------------------------------------
// Fused projections, dual-B z-slices, 128x64 tile, BK=64:
// z=0: A=query (f32, cvt in staging), B={Btq,Btqo} -> qp(f16), offs(f16)
// z=1: A=in16 (f16),                 B={Btk,Btv}  -> head-major packed kv
// ---------------------------------------------------------------------------
__global__ __launch_bounds__(256) void gemm_qkv(
    const float* __restrict__ queryF, const unsigned short* __restrict__ in16,
    const unsigned short* __restrict__ Btq,
    const unsigned short* __restrict__ Btk,
    const unsigned short* __restrict__ Btv,
    const unsigned short* __restrict__ Btqo,
    const float* __restrict__ bq, const float* __restrict__ bk,
    const float* __restrict__ bv, const float* __restrict__ bqo,
    unsigned short* __restrict__ qp_out, unsigned* __restrict__ kv_out,
    unsigned short* __restrict__ offs_out, int M) {
  const int P = 72;
  __shared__ short As[128 * P], B1[64 * P], B2[64 * P];
  int z = blockIdx.z;
  const unsigned short* Bt1 = (z == 0) ? Btq : Btk;
  const unsigned short* Bt2 = (z == 0) ? Btqo : Btv;
  int tid = threadIdx.x;
  int m0 = blockIdx.x * 128, n0 = blockIdx.y * 64;
  int w = tid >> 6, l = tid & 63;
  int r = l & 15, g = l >> 4;
  int mi = (w >> 1) * 64, ni = (w & 1) * 32;
  int arow = tid >> 1, ach = (tid & 1) * 32;
  int brow = tid >> 2, bch = (tid & 3) * 16;

  f32x4 acc1[4][2], acc2[4][2];
  #pragma unroll
  for (int a = 0; a < 4; a++)
    #pragma unroll
    for (int b = 0; b < 2; b++) {
      acc1[a][b] = (f32x4){0.f, 0.f, 0.f, 0.f};
      acc2[a][b] = (f32x4){0.f, 0.f, 0.f, 0.f};
    }

  for (int k0 = 0; k0 < 256; k0 += 64) {
    int gm = m0 + arow;
    if (z == 0) {
      #pragma unroll
      for (int t = 0; t < 4; t++) {
        f16x8 hv = {0, 0, 0, 0, 0, 0, 0, 0};
        if (gm < M) {
          const float* src = queryF + (size_t)gm * 256 + k0 + ach + t * 8;
          float4 u0 = *(const float4*)src;
          float4 u1 = *(const float4*)(src + 4);
          hv = (f16x8){(_Float16)u0.x, (_Float16)u0.y, (_Float16)u0.z, (_Float16)u0.w,
                       (_Float16)u1.x, (_Float16)u1.y, (_Float16)u1.z, (_Float16)u1.w};
        }
        *(f16x8*)&As[arow * P + ach + t * 8] = hv;
      }
    } else {
      short8v a0 = {0,0,0,0,0,0,0,0}, a1 = a0, a2 = a0, a3 = a0;
      if (gm < M) {
        const unsigned short* src = in16 + (size_t)gm * 256 + k0 + ach;
        a0 = *(const short8v*)src;
        a1 = *(const short8v*)(src + 8);
        a2 = *(const short8v*)(src + 16);
        a3 = *(const short8v*)(src + 24);
      }
      *(short8v*)&As[arow * P + ach] = a0;
      *(short8v*)&As[arow * P + ach + 8] = a1;
      *(short8v*)&As[arow * P + ach + 16] = a2;
      *(short8v*)&As[arow * P + ach + 24] = a3;
    }
    {
      const unsigned short* bsrc = Bt1 + (size_t)(n0 + brow) * 256 + k0 + bch;
      *(short8v*)&B1[brow * P + bch] = *(const short8v*)bsrc;
      *(short8v*)&B1[brow * P + bch + 8] = *(const short8v*)(bsrc + 8);
      const unsigned short* bsrc2 = Bt2 + (size_t)(n0 + brow) * 256 + k0 + bch;
      *(short8v*)&B2[brow * P + bch] = *(const short8v*)bsrc2;
      *(short8v*)&B2[brow * P + bch + 8] = *(const short8v*)(bsrc2 + 8);
    }
    __syncthreads();

    f16x8 af[4][2], b1f[2][2], b2f[2][2];
    #pragma unroll
    for (int a = 0; a < 4; a++)
      #pragma unroll
      for (int ks = 0; ks < 2; ks++)
        af[a][ks] = *(f16x8*)&As[(mi + a * 16 + r) * P + ks * 32 + g * 8];
    #pragma unroll
    for (int b = 0; b < 2; b++)
      #pragma unroll
      for (int ks = 0; ks < 2; ks++) {
        b1f[b][ks] = *(f16x8*)&B1[(ni + b * 16 + r) * P + ks * 32 + g * 8];
        b2f[b][ks] = *(f16x8*)&B2[(ni + b * 16 + r) * P + ks * 32 + g * 8];
      }
    #pragma unroll
    for (int a = 0; a < 4; a++)
      #pragma unroll
      for (int b = 0; b < 2; b++)
        #pragma unroll
        for (int ks = 0; ks < 2; ks++) {
          acc1[a][b] = __builtin_amdgcn_mfma_f32_16x16x32_f16(af[a][ks], b1f[b][ks], acc1[a][b], 0, 0, 0);
          acc2[a][b] = __builtin_amdgcn_mfma_f32_16x16x32_f16(af[a][ks], b2f[b][ks], acc2[a][b], 0, 0, 0);
        }
    __syncthreads();
  }

  #pragma unroll
  for (int a = 0; a < 4; a++)
    #pragma unroll
    for (int b = 0; b < 2; b++) {
      int col = n0 + ni + b * 16 + r;
      if (z == 0) {
        float bc1 = bq[col], bc2 = bqo[col];
        #pragma unroll
        for (int i = 0; i < 4; i++) {
          int row = m0 + mi + a * 16 + g * 4 + i;
          if (row < M) {
            qp_out[(size_t)row * 256 + col] = f2h(acc1[a][b][i] + bc1);
            offs_out[(size_t)row * 256 + col] = f2h(acc2[a][b][i] + bc2);
          }
        }
      } else {
        float bkc = bk[col], bvc = bv[col];
        int hh = col >> 5, cc = col & 31;
        #pragma unroll
        for (int i = 0; i < 4; i++) {
          int row = m0 + mi + a * 16 + g * 4 + i;
          if (row < M) {
            unsigned kh = f2h(acc1[a][b][i] + bkc);
            unsigned vh = f2h(acc2[a][b][i] + bvc);
            kv_out[((size_t)hh * LEN_IN + row) * 32 + cc] = kh | (vh << 16);
          }
        }
      }
    }
}

// ---------------------------------------------------------------------------
// Output projection: A f16 (attn), f32 out, 128x64 tile BK=64.
// ---------------------------------------------------------------------------
__global__ __launch_bounds__(256) void gemm_out(
    const unsigned short* __restrict__ A,
    const unsigned short* __restrict__ Bt,
    const float* __restrict__ bias, float* __restrict__ C, int M) {
  const int P = 72;
  __shared__ short As[128 * P], Bs[64 * P];
  int tid = threadIdx.x;
  int m0 = blockIdx.x * 128, n0 = blockIdx.y * 64;
  int w = tid >> 6, l = tid & 63;
  int r = l & 15, g = l >> 4;
  int mi = (w >> 1) * 64, ni = (w & 1) * 32;
  int arow = tid >> 1, ach = (tid & 1) * 32;
  int brow = tid >> 2, bch = (tid & 3) * 16;

  f32x4 acc[4][2];
  #pragma unroll
  for (int a = 0; a < 4; a++)
    #pragma unroll
    for (int b = 0; b < 2; b++) acc[a][b] = (f32x4){0.f, 0.f, 0.f, 0.f};

  for (int k0 = 0; k0 < 256; k0 += 64) {
    int gm = m0 + arow;
    short8v a0 = {0,0,0,0,0,0,0,0}, a1 = a0, a2 = a0, a3 = a0;
    if (gm < M) {
      const unsigned short* src = A + (size_t)gm * 256 + k0 + ach;
      a0 = *(const short8v*)src;
      a1 = *(const short8v*)(src + 8);
      a2 = *(const short8v*)(src + 16);
      a3 = *(const short8v*)(src + 24);
    }
    *(short8v*)&As[arow * P + ach] = a0;
    *(short8v*)&As[arow * P + ach + 8] = a1;
    *(short8v*)&As[arow * P + ach + 16] = a2;
    *(short8v*)&As[arow * P + ach + 24] = a3;
    const unsigned short* bsrc = Bt + (size_t)(n0 + brow) * 256 + k0 + bch;
    *(short8v*)&Bs[brow * P + bch] = *(const short8v*)bsrc;
    *(short8v*)&Bs[brow * P + bch + 8] = *(const short8v*)(bsrc + 8);
    __syncthreads();

    f16x8 af[4][2], bf[2][2];
    #pragma unroll
    for (int a = 0; a < 4; a++)
      #pragma unroll
      for (int ks = 0; ks < 2; ks++)
        af[a][ks] = *(f16x8*)&As[(mi + a * 16 + r) * P + ks * 32 + g * 8];
    #pragma unroll
    for (int b = 0; b < 2; b++)
      #pragma unroll
      for (int ks = 0; ks < 2; ks++)
        bf[b][ks] = *(f16x8*)&Bs[(ni + b * 16 + r) * P + ks * 32 + g * 8];
    #pragma unroll
    for (int a = 0; a < 4; a++)
      #pragma unroll
      for (int b = 0; b < 2; b++)
        #pragma unroll
        for (int ks = 0; ks < 2; ks++)
          acc[a][b] = __builtin_amdgcn_mfma_f32_16x16x32_f16(af[a][ks], bf[b][ks], acc[a][b], 0, 0, 0);
    __syncthreads();
  }
  #pragma unroll
  for (int a = 0; a < 4; a++)
    #pragma unroll
    for (int b = 0; b < 2; b++) {
      int col = n0 + ni + b * 16 + r;
      float bc = bias[col];
      #pragma unroll
      for (int i = 0; i < 4; i++) {
        int row = m0 + mi + a * 16 + g * 4 + i;
        if (row < M) C[(size_t)row * 256 + col] = acc[a][b][i] + bc;
      }
    }
}

// ---------------------------------------------------------------------------
// Sampling + attention v9 (proven ~55 us): 1 (q,h)/wave, lean addressing,
// register softmax, head-major packed f16 kv, fdot2 dot.
// ---------------------------------------------------------------------------
__global__ __launch_bounds__(256) void sample_attn(
    const unsigned short* __restrict__ qp,    // f16 (LEN,256)
    const unsigned short* __restrict__ offs,  // f16 (LEN,256)
    const float* __restrict__ rp,             // f32 (LEN,8)
    const unsigned* __restrict__ kv,          // packed f16 {k|v<<16}, [h][pix][32]
    unsigned short* __restrict__ attn_out) {  // f16 (LEN,256)
  __shared__ float vbuf[4][16][36];

  int tid = threadIdx.x;
  int wslot = tid >> 6;
  int lane = tid & 63;
  int wid = blockIdx.x * 4 + wslot;
  int q = wid >> 3;
  int h = wid & 7;

  int pt = lane >> 2;        // point 0..15
  int c8 = (lane & 3) * 8;   // channel chunk base
  int l = pt >> 2, pp = pt & 3;
  int W = 112 >> l;
  int start = (int)((50176u - (50176u >> (2 * l))) / 3u);  // 0,12544,15680,16464

  // direct pair loads (same addr across the 4 chunk-lanes -> HW broadcast)
  f16x2 offp = u2h(*(const unsigned*)(offs + (size_t)q * 256 + h * 32 + pt * 2));
  float2 rpp = *(const float2*)(rp + (size_t)q * 8 + l * 2);

  float x = rpp.x * (float)W + (float)offp[0] - 0.5f;
  float y = rpp.y * (float)W + (float)offp[1] - 0.5f;
  float x0f = floorf(x), y0f = floorf(y);
  float lx = x - x0f, ly = y - y0f;
  int x0 = (int)x0f, y0 = (int)y0f;
  float wx0 = 1.f - lx, wy0 = 1.f - ly;

  int Wm1 = W - 1;
  int x0c = min(max(x0, 0), Wm1), x1c = min(max(x0 + 1, 0), Wm1);
  int y0c = min(max(y0, 0), Wm1), y1c = min(max(y0 + 1, 0), Wm1);
  bool x0v = (unsigned)x0 < (unsigned)W, x1v = (unsigned)(x0 + 1) < (unsigned)W;
  bool y0v = (unsigned)y0 < (unsigned)W, y1v = (unsigned)(y0 + 1) < (unsigned)W;
  float w00 = (x0v && y0v) ? wy0 * wx0 : 0.f;
  float w01 = (x1v && y0v) ? wy0 * lx : 0.f;
  float w10 = (x0v && y1v) ? ly * wx0 : 0.f;
  float w11 = (x1v && y1v) ? ly * lx : 0.f;

  const unsigned* kvh = kv + (size_t)h * LEN_IN * 32 + c8;
  const unsigned* row0 = kvh + (size_t)(start + y0c * W) * 32;
  const unsigned* row1 = kvh + (size_t)(start + y1c * W) * 32;

  f16x2 acc[8];
  #pragma unroll
  for (int j = 0; j < 8; j++) acc[j] = (f16x2){(_Float16)0.f, (_Float16)0.f};

  const unsigned* taddr[4] = {row0 + (size_t)x0c * 32, row0 + (size_t)x1c * 32,
                              row1 + (size_t)x0c * 32, row1 + (size_t)x1c * 32};
  float twgt[4] = {w00, w01, w10, w11};
  #pragma unroll
  for (int tap = 0; tap < 4; tap++) {
    uint4 u0 = *(const uint4*)taddr[tap];
    uint4 u1 = *(const uint4*)(taddr[tap] + 4);
    _Float16 wh = (_Float16)twgt[tap];
    f16x2 w2 = {wh, wh};
    acc[0] += w2 * u2h(u0.x);
    acc[1] += w2 * u2h(u0.y);
    acc[2] += w2 * u2h(u0.z);
    acc[3] += w2 * u2h(u0.w);
    acc[4] += w2 * u2h(u1.x);
    acc[5] += w2 * u2h(u1.y);
    acc[6] += w2 * u2h(u1.z);
    acc[7] += w2 * u2h(u1.w);
  }

  // q . k via fdot2 on paired k's (low halves of acc)
  uint4 qa = *(const uint4*)(qp + (size_t)q * 256 + h * 32 + c8);
  float dot = 0.f;
  f16x2 kp;
  kp[0] = acc[0][0]; kp[1] = acc[1][0];
  dot = __builtin_amdgcn_fdot2(u2h(qa.x), kp, dot, false);
  kp[0] = acc[2][0]; kp[1] = acc[3][0];
  dot = __builtin_amdgcn_fdot2(u2h(qa.y), kp, dot, false);
  kp[0] = acc[4][0]; kp[1] = acc[5][0];
  dot = __builtin_amdgcn_fdot2(u2h(qa.z), kp, dot, false);
  kp[0] = acc[6][0]; kp[1] = acc[7][0];
  dot = __builtin_amdgcn_fdot2(u2h(qa.w), kp, dot, false);
  dot += __shfl_xor(dot, 1, 64);
  dot += __shfl_xor(dot, 2, 64);

  // register softmax (no max-sub: |logit| small), sum via shfl
  float e = __expf(dot * 0.17677669529663687f);
  float s = e;
  s += __shfl_xor(s, 4, 64);
  s += __shfl_xor(s, 8, 64);
  s += __shfl_xor(s, 16, 64);
  s += __shfl_xor(s, 32, 64);
  float wsc = e / s;

  // store softmax-scaled v (high halves) into LDS
  float4 v0 = {wsc * (float)acc[0][1], wsc * (float)acc[1][1],
               wsc * (float)acc[2][1], wsc * (float)acc[3][1]};
  float4 v1 = {wsc * (float)acc[4][1], wsc * (float)acc[5][1],
               wsc * (float)acc[6][1], wsc * (float)acc[7][1]};
  *(float4*)&vbuf[wslot][pt][c8] = v0;
  *(float4*)&vbuf[wslot][pt][c8 + 4] = v1;
  __syncthreads();

  // output: all 64 lanes — half-wave sums 8 points each, then 1 shfl merge
  int half = lane >> 5;
  int c = lane & 31;
  float o = 0.f;
  #pragma unroll
  for (int p = 0; p < 8; p++) o += vbuf[wslot][half * 8 + p][c];
  o += __shfl_xor(o, 32, 64);
  if (lane < 32)
    attn_out[(size_t)q * 256 + h * 32 + c] = f2h(o);
}

extern "C" void kernel_launch(void* const* d_in, const int* in_sizes, int n_in,
                              void* d_out, int out_size, void* d_ws, size_t ws_size,
                              hipStream_t stream) {
  const float* query = (const float*)d_in[0];
  const float* rp    = (const float*)d_in[1];
  const float* inp   = (const float*)d_in[2];
  const float* W_q   = (const float*)d_in[5];
  const float* b_q   = (const float*)d_in[6];
  const float* W_k   = (const float*)d_in[7];
  const float* b_k   = (const float*)d_in[8];
  const float* W_v   = (const float*)d_in[9];
  const float* b_v   = (const float*)d_in[10];
  const float* W_o   = (const float*)d_in[11];
  const float* b_o   = (const float*)d_in[12];
  const float* W_off = (const float*)d_in[13];
  const float* b_off = (const float*)d_in[14];
  float* out = (float*)d_out;

  const size_t nelem = (size_t)LEN_IN * D_MODEL;  // 4,264,960
  unsigned short* in16  = (unsigned short*)d_ws;
  unsigned short* qp    = in16 + nelem;
  unsigned short* offsb = qp + nelem;
  unsigned short* attn  = offsb + nelem;
  unsigned* kvp = (unsigned*)(attn + nelem);
  unsigned short* Btq   = (unsigned short*)(kvp + nelem);
  unsigned short* Btk   = Btq + 256 * 256;
  unsigned short* Btv   = Btk + 256 * 256;
  unsigned short* Bto   = Btv + 256 * 256;
  unsigned short* Btqo  = Bto + 256 * 256;
  float* bqo = (float*)(Btqo + 256 * 256);

  dim3 blk(256);
  dim3 ggrid((LEN_IN + 127) / 128, D_MODEL / 64);      // (131, 4)
  dim3 ggrid2((LEN_IN + 127) / 128, D_MODEL / 64, 2);  // {q+off, kv}

  mega_prep<<<2145, blk, 0, stream>>>(inp, W_q, W_k, W_v, W_off, W_o,
                                      b_q, b_off, in16,
                                      Btq, Btk, Btv, Bto, Btqo, bqo);

  gemm_qkv<<<ggrid2, blk, 0, stream>>>(query, in16, Btq, Btk, Btv, Btqo,
                                       b_q, b_k, b_v, bqo,
                                       qp, kvp, offsb, LEN_IN);

  int n_blocks = LEN_IN * N_HEADS / 4;  // 33320
  sample_attn<<<n_blocks, blk, 0, stream>>>(qp, offsb, rp, kvp, attn);

  gemm_out<<<ggrid, blk, 0, stream>>>(attn, Bto, b_o, out, LEN_IN);
}